// Round 1
// baseline (911.223 us; speedup 1.0000x reference)
//
#include <hip/hip_runtime.h>

#define EPS 1e-5f
// sizes
#define NB 8
#define NC 64
#define NH 224
#define NW 224
#define PLANE (NH*NW)            // 50176
#define NPIX (NB*PLANE)          // 401408 per channel
#define OUT_ELEMS (NB*NC*PLANE)  // 25690112

// ws layout (floats):
// [0, 36864)    : Wm transposed  wt2[ic][tap][oc]   (64*9*64)
// [36864,36928) : per-channel sum
// [36928,36992) : per-channel sumsq
#define WT2_FLOATS (64*9*64)

// ---------------------------------------------------------------------------
// KW: merge 1x1 conv into the 3x3 ternary conv:  Wm[o][i][tap] = sum_k w1[o][k]*wb[k][i][tap]
// stored transposed for scalar-load access in K1: wt2[(ic*9+tap)*64 + oc]
// Also zero-inits the stats region.
__global__ void kw_merge(const float* __restrict__ w_bin,
                         const float* __restrict__ w1x1,
                         float* __restrict__ ws)
{
    const int ic  = blockIdx.x;      // 0..63
    const int oc  = threadIdx.x;     // 0..63
    const int tap = threadIdx.y;     // 0..8
    float acc = 0.f;
    for (int k = 0; k < 64; ++k)
        acc += w1x1[oc*64 + k] * w_bin[(k*64 + ic)*9 + tap];
    ws[(ic*9 + tap)*64 + oc] = acc;
    if (ic == 0 && tap < 2)
        ws[WT2_FLOATS + tap*64 + oc] = 0.f;   // zero stats
}

// ---------------------------------------------------------------------------
// K1: merged 3x3 conv + bias. Block = 4 rows x 64 cols, 4 waves (lane = column).
// x tile staged in LDS in two 32-input-channel passes. Weights via uniform
// (scalar) loads from ws. Each lane accumulates all 64 output channels.
__global__ __launch_bounds__(256)
void k1_conv(const float* __restrict__ x,
             const float* __restrict__ wt2,
             const float* __restrict__ b1x1,
             float* __restrict__ y)
{
    __shared__ float xs[32][6][68];

    const int gx   = blockIdx.x;          // 0..3 column strip (64 wide)
    const int gy   = blockIdx.y;          // 0..55 row group (4 rows)
    const int b    = blockIdx.z;          // batch
    const int tid  = threadIdx.x;
    const int wv   = tid >> 6;            // wave = row within group (0..3)
    const int lane = tid & 63;            // column within strip
    const int x0   = gx * 64;
    const int y0   = gy * 4;
    const int col  = x0 + lane;

    float acc[64];
#pragma unroll
    for (int o = 0; o < 64; ++o) acc[o] = b1x1[o];

#pragma unroll 1
    for (int pass = 0; pass < 2; ++pass) {
        __syncthreads();
        // cooperative load: 32 ic x 6 rows x 66 cols (halo, zero-padded)
#pragma unroll 1
        for (int idx = tid; idx < 32*6*66; idx += 256) {
            const int c  = idx % 66;
            const int rr = (idx / 66) % 6;
            const int ic = idx / (66*6);
            const int gr = y0 - 1 + rr;
            const int gc = x0 - 1 + c;
            float v = 0.f;
            if ((unsigned)gr < (unsigned)NH && (unsigned)gc < (unsigned)NW)
                v = x[((size_t)(b*NC + pass*32 + ic)*NH + gr)*NW + gc];
            xs[ic][rr][c] = v;
        }
        __syncthreads();

        const float* wp = wt2 + pass*32*9*64;
#pragma unroll 1
        for (int ic = 0; ic < 32; ++ic) {
            float xv[9];
#pragma unroll
            for (int ky = 0; ky < 3; ++ky)
#pragma unroll
                for (int kx = 0; kx < 3; ++kx)
                    xv[ky*3 + kx] = xs[ic][wv + ky][lane + kx];

            const float* wq = wp + ic*9*64;
#pragma unroll
            for (int og = 0; og < 8; ++og)
#pragma unroll
                for (int t = 0; t < 9; ++t) {
#pragma unroll
                    for (int j = 0; j < 8; ++j)
                        acc[og*8 + j] += wq[t*64 + og*8 + j] * xv[t];
                }
        }
    }

    if (col < NW) {
        const int row = y0 + wv;
        float* yp = y + ((size_t)b*NC)*PLANE + (size_t)row*NW + col;
#pragma unroll
        for (int o = 0; o < 64; ++o)
            yp[(size_t)o*PLANE] = acc[o];
    }
}

// ---------------------------------------------------------------------------
// K2: per-channel sum / sumsq over (B,H,W). grid = 64 channels x 8 batches.
__global__ __launch_bounds__(256)
void k2_stats(const float* __restrict__ y, float* __restrict__ stats)
{
    const int c = blockIdx.x & 63;
    const int b = blockIdx.x >> 6;
    const float4* p = (const float4*)(y + ((size_t)(b*NC + c))*PLANE);
    float s = 0.f, s2 = 0.f;
    for (int i = threadIdx.x; i < PLANE/4; i += 256) {
        float4 v = p[i];
        s  += v.x + v.y + v.z + v.w;
        s2 += v.x*v.x + v.y*v.y + v.z*v.z + v.w*v.w;
    }
#pragma unroll
    for (int off = 32; off; off >>= 1) {
        s  += __shfl_down(s, off);
        s2 += __shfl_down(s2, off);
    }
    __shared__ float rs[4], rs2[4];
    const int lane = threadIdx.x & 63, w = threadIdx.x >> 6;
    if (lane == 0) { rs[w] = s; rs2[w] = s2; }
    __syncthreads();
    if (threadIdx.x == 0) {
        float ts = 0.f, ts2 = 0.f;
#pragma unroll
        for (int i = 0; i < 4; ++i) { ts += rs[i]; ts2 += rs2[i]; }
        atomicAdd(&stats[c],      ts);
        atomicAdd(&stats[64 + c], ts2);
    }
}

// ---------------------------------------------------------------------------
// K3: in-place BN (batch stats) + leaky-relu + clamp.  leaky(0.1) followed by
// clip(0,255) is exactly clamp(t,0,255) since negative leaked values clip to 0.
__global__ __launch_bounds__(256)
void k3_bn(float* __restrict__ y, const float* __restrict__ stats,
           const float* __restrict__ gamma, const float* __restrict__ beta)
{
    const float inv_n = 1.f / (float)NPIX;
    const long n4 = OUT_ELEMS / 4;
    for (long i = (long)blockIdx.x*256 + threadIdx.x; i < n4; i += (long)gridDim.x*256) {
        const int c = (int)((i / (PLANE/4)) & 63);
        const float mean = stats[c] * inv_n;
        const float var  = stats[64 + c] * inv_n - mean*mean;
        const float sc   = gamma[c] * rsqrtf(var + EPS);
        const float sh   = beta[c] - mean*sc;
        float4 v = ((float4*)y)[i];
        v.x = fminf(fmaxf(v.x*sc + sh, 0.f), 255.f);
        v.y = fminf(fmaxf(v.y*sc + sh, 0.f), 255.f);
        v.z = fminf(fmaxf(v.z*sc + sh, 0.f), 255.f);
        v.w = fminf(fmaxf(v.w*sc + sh, 0.f), 255.f);
        ((float4*)y)[i] = v;
    }
}

// ---------------------------------------------------------------------------
extern "C" void kernel_launch(void* const* d_in, const int* in_sizes, int n_in,
                              void* d_out, int out_size, void* d_ws, size_t ws_size,
                              hipStream_t stream)
{
    const float* x     = (const float*)d_in[0];
    const float* w_bin = (const float*)d_in[1];
    const float* w1x1  = (const float*)d_in[2];
    const float* b1x1  = (const float*)d_in[3];
    const float* gamma = (const float*)d_in[4];
    const float* beta  = (const float*)d_in[5];
    float* out = (float*)d_out;
    float* wt2   = (float*)d_ws;
    float* stats = wt2 + WT2_FLOATS;

    kw_merge<<<64, dim3(64, 9), 0, stream>>>(w_bin, w1x1, wt2);
    k1_conv<<<dim3(4, 56, NB), 256, 0, stream>>>(x, wt2, b1x1, out);
    k2_stats<<<512, 256, 0, stream>>>(out, stats);
    k3_bn<<<2048, 256, 0, stream>>>(out, stats, gamma, beta);
}

// Round 5
// 398.262 us; speedup vs baseline: 2.2880x; 2.2880x over previous
//
#include <hip/hip_runtime.h>

#define EPS 1e-5f
#define NB 8
#define NC 64
#define NH 224
#define NW 224
#define PLANE (NH*NW)            // 50176
#define NPIX (NB*PLANE)          // 401408
#define OUT_ELEMS (NB*NC*PLANE)  // 25690112

typedef __attribute__((ext_vector_type(8)))  short short8;
typedef __attribute__((ext_vector_type(16))) float floatx16;
typedef unsigned int u32;

// bf16 helpers (RNE)
__device__ __forceinline__ unsigned short f2bf(float f) {
    unsigned u = __float_as_uint(f);
    unsigned r = (u + 0x7fffu + ((u >> 16) & 1u)) >> 16;
    return (unsigned short)r;
}
__device__ __forceinline__ float bf2f(unsigned short s) {
    return __uint_as_float(((unsigned)s) << 16);
}

// ws layout (bytes):
//   [0, 147456)    wt: [tap 9][chunk 4] slabs of 4096B:
//                  { wh[oc 64][icl 16] 2048B | wl[oc 64][icl 16] 2048B }
//   [147456,+512)  stats: 64 sum + 64 sumsq floats
#define WT_BYTES (9*4*4096)

// B slab layout (per hi/lo slab, 24960 B):
//   [h 2][rr 6][cc 130][icl&7 -> 8 bf16 = 16B granule]
// byte(h, rr, cc, iclLow) = ((h*6 + rr)*130 + cc)*16 + iclLow*2
// Reads (lane=cc consecutive, 16B each) are contiguous -> bank-conflict-free.
// No XOR swizzle: plain bijective layout (r2/r4 failed on a non-bijective XOR).

// ---------------------------------------------------------------------------
// KW: merge 1x1 into 3x3: Wm[o][i][tap] = sum_k w1[o][k]*wb[k][i][tap];
// split into bf16 hi/lo, store plain [tap][chunk][hi|lo][oc][icl].
__global__ void kw_merge(const float* __restrict__ w_bin,
                         const float* __restrict__ w1x1,
                         unsigned char* __restrict__ ws)
{
    const int ic  = blockIdx.x;      // 0..63
    const int oc  = threadIdx.x;     // 0..63
    const int tap = threadIdx.y;     // 0..8
    float acc = 0.f;
    for (int k = 0; k < 64; ++k)
        acc += w1x1[oc*64 + k] * w_bin[(k*64 + ic)*9 + tap];
    const unsigned short wh = f2bf(acc);
    const unsigned short wl = f2bf(acc - bf2f(wh));
    const int chunk = ic >> 4, icl = ic & 15;
    const int base  = (tap*4 + chunk) * 4096;
    const int sb    = oc*32 + icl*2;
    *(unsigned short*)(ws + base + sb)        = wh;
    *(unsigned short*)(ws + base + 2048 + sb) = wl;
    if (blockIdx.x == 0 && tap < 2)
        ((float*)(ws + WT_BYTES))[tap*64 + oc] = 0.f;
}

// ---------------------------------------------------------------------------
// K1: merged conv via bf16 MFMA (3 combos: wh*xh, wh*xl, wl*xh).
// Block: 4 waves; wave w owns output row r0+w: 64 oc x 128 cols.
// A fragments: direct global->VGPR loads (L1-hot, prefetched 1 tap ahead).
// B (x): LDS, plain [h][rr][cc][8] layout, hi slab @0, lo slab @24960.
__global__ __launch_bounds__(256, 2)
void k1_conv(const float* __restrict__ x,
             const unsigned char* __restrict__ wt,
             const float* __restrict__ b1x1,
             float* __restrict__ y)
{
    __shared__ char smem[49920];
    const int tid  = threadIdx.x;
    const int w    = tid >> 6;         // wave = row in tile
    const int lane = tid & 63;
    const int l31  = lane & 31;
    const int h    = lane >> 5;
    const int c0   = blockIdx.x * 96;  // col strips [0,128) and [96,224)
    const int r0   = blockIdx.y * 4;
    const int b    = blockIdx.z;

    floatx16 c[2][4];
#pragma unroll
    for (int mf = 0; mf < 2; ++mf)
#pragma unroll
        for (int nf = 0; nf < 4; ++nf)
#pragma unroll
            for (int r = 0; r < 16; ++r) c[mf][nf][r] = 0.f;

    const unsigned alane = (unsigned)(l31*32 + (h << 4));
    auto ldA = [&](int slab, int part) -> short8 {
        return *(const short8*)(wt + (size_t)slab*4096u + (unsigned)part + alane);
    };

    // preload A for (tap0, chunk0)
    short8 ah0 = ldA(0, 0), ah1 = ldA(0, 1024), al0 = ldA(0, 2048), al1 = ldA(0, 3072);

#pragma unroll 1
    for (int chunk = 0; chunk < 4; ++chunk) {
        // ---- stage x chunk into LDS (fp32 -> bf16 hi/lo) ----
        const float* xc = x + ((size_t)(b*NC + chunk*16)*NH)*NW;
#pragma unroll 1
        for (int i = tid; i < 7680; i += 256) {
            const unsigned cclow = (unsigned)i & 31u;
            const unsigned icp   = ((unsigned)i >> 5) & 7u;   // ic pair 0..7
            const unsigned t     = (unsigned)i >> 8;          // 0..29
            const unsigned ccb   = t % 5u;
            const unsigned rr    = t / 5u;                    // 0..5
            const unsigned cc    = ccb*32u + cclow;
            if (cc < 130u) {
                const int gr = r0 - 1 + (int)rr;
                const int gc = c0 - 1 + (int)cc;
                float v0 = 0.f, v1 = 0.f;
                if ((unsigned)gr < (unsigned)NH && (unsigned)gc < (unsigned)NW) {
                    const float* p = xc + ((size_t)(icp*2u)*NH + gr)*NW + gc;
                    v0 = p[0];
                    v1 = p[PLANE];
                }
                const unsigned short h0 = f2bf(v0), h1 = f2bf(v1);
                const unsigned short l0 = f2bf(v0 - bf2f(h0)), l1 = f2bf(v1 - bf2f(h1));
                // icl pair (2icp, 2icp+1): half hh = icp>>2, within-half u32 slot icp&3
                const unsigned hh   = icp >> 2;
                const unsigned byte = ((hh*6u + rr)*130u + cc)*16u + (icp & 3u)*4u;
                *(u32*)(smem + byte)         = (u32)h0 | ((u32)h1 << 16);
                *(u32*)(smem + 24960 + byte) = (u32)l0 | ((u32)l1 << 16);
            }
        }
        __syncthreads();   // xs ready

#pragma unroll 1
        for (int tap = 0; tap < 9; ++tap) {
            // prefetch next tap's A fragments (global->reg; safe across barriers)
            int ntap = tap + 1, nchunk = chunk;
            if (ntap == 9) { ntap = 0; nchunk = chunk + 1; }
            short8 nh0 = ah0, nh1 = ah1, nl0 = al0, nl1 = al1;
            if (nchunk < 4) {
                const int ns = ntap*4 + nchunk;
                nh0 = ldA(ns, 0);    nh1 = ldA(ns, 1024);
                nl0 = ldA(ns, 2048); nl1 = ldA(ns, 3072);
            }

            const int dy = tap / 3, dx = tap - dy*3;
            const unsigned bro = ((unsigned)(h*6 + w + dy)*130u + (unsigned)dx + (unsigned)l31)*16u;
#pragma unroll
            for (int nf = 0; nf < 4; ++nf) {
                const unsigned off = bro + (unsigned)nf*512u;   // nf*32 cols * 16B
                short8 bh = *(const short8*)(smem + off);
                short8 bl = *(const short8*)(smem + (24960u + off));
                c[0][nf] = __builtin_amdgcn_mfma_f32_32x32x16_bf16(ah0, bh, c[0][nf], 0, 0, 0);
                c[1][nf] = __builtin_amdgcn_mfma_f32_32x32x16_bf16(ah1, bh, c[1][nf], 0, 0, 0);
                c[0][nf] = __builtin_amdgcn_mfma_f32_32x32x16_bf16(ah0, bl, c[0][nf], 0, 0, 0);
                c[1][nf] = __builtin_amdgcn_mfma_f32_32x32x16_bf16(ah1, bl, c[1][nf], 0, 0, 0);
                c[0][nf] = __builtin_amdgcn_mfma_f32_32x32x16_bf16(al0, bh, c[0][nf], 0, 0, 0);
                c[1][nf] = __builtin_amdgcn_mfma_f32_32x32x16_bf16(al1, bh, c[1][nf], 0, 0, 0);
            }
            ah0 = nh0; ah1 = nh1; al0 = nl0; al1 = nl1;
        }
        __syncthreads();   // all waves done with xs before next chunk overwrites
    }

    // ---- epilogue: add bias, store ----
    const int row = r0 + w;
#pragma unroll
    for (int mf = 0; mf < 2; ++mf)
#pragma unroll
        for (int r = 0; r < 16; ++r) {
            const int oc = mf*32 + (r & 3) + 8*(r >> 2) + 4*h;
            const float bias = b1x1[oc];
            float* yp = y + ((size_t)(b*NC + oc)*NH + row)*NW + c0 + l31;
#pragma unroll
            for (int nf = 0; nf < 4; ++nf)
                yp[nf*32] = c[mf][nf][r] + bias;
        }
}

// ---------------------------------------------------------------------------
// K2: per-channel sum / sumsq over (B,H,W). grid = 64 channels x 8 batches.
__global__ __launch_bounds__(256)
void k2_stats(const float* __restrict__ y, float* __restrict__ stats)
{
    const int c = blockIdx.x & 63;
    const int b = blockIdx.x >> 6;
    const float4* p = (const float4*)(y + ((size_t)(b*NC + c))*PLANE);
    float s = 0.f, s2 = 0.f;
    for (int i = threadIdx.x; i < PLANE/4; i += 256) {
        float4 v = p[i];
        s  += v.x + v.y + v.z + v.w;
        s2 += v.x*v.x + v.y*v.y + v.z*v.z + v.w*v.w;
    }
#pragma unroll
    for (int off = 32; off; off >>= 1) {
        s  += __shfl_down(s, off);
        s2 += __shfl_down(s2, off);
    }
    __shared__ float rs[4], rs2[4];
    const int lane = threadIdx.x & 63, wv = threadIdx.x >> 6;
    if (lane == 0) { rs[wv] = s; rs2[wv] = s2; }
    __syncthreads();
    if (threadIdx.x == 0) {
        float ts = 0.f, ts2 = 0.f;
#pragma unroll
        for (int i = 0; i < 4; ++i) { ts += rs[i]; ts2 += rs2[i]; }
        atomicAdd(&stats[c],      ts);
        atomicAdd(&stats[64 + c], ts2);
    }
}

// ---------------------------------------------------------------------------
// K3: in-place BN (batch stats) + leaky + clamp (== clamp(t,0,255)).
__global__ __launch_bounds__(256)
void k3_bn(float* __restrict__ y, const float* __restrict__ stats,
           const float* __restrict__ gamma, const float* __restrict__ beta)
{
    const float inv_n = 1.f / (float)NPIX;
    const long n4 = OUT_ELEMS / 4;
    for (long i = (long)blockIdx.x*256 + threadIdx.x; i < n4; i += (long)gridDim.x*256) {
        const int c = (int)((i / (PLANE/4)) & 63);
        const float mean = stats[c] * inv_n;
        const float var  = stats[64 + c] * inv_n - mean*mean;
        const float sc   = gamma[c] * rsqrtf(var + EPS);
        const float sh   = beta[c] - mean*sc;
        float4 v = ((float4*)y)[i];
        v.x = fminf(fmaxf(v.x*sc + sh, 0.f), 255.f);
        v.y = fminf(fmaxf(v.y*sc + sh, 0.f), 255.f);
        v.z = fminf(fmaxf(v.z*sc + sh, 0.f), 255.f);
        v.w = fminf(fmaxf(v.w*sc + sh, 0.f), 255.f);
        ((float4*)y)[i] = v;
    }
}

// ---------------------------------------------------------------------------
extern "C" void kernel_launch(void* const* d_in, const int* in_sizes, int n_in,
                              void* d_out, int out_size, void* d_ws, size_t ws_size,
                              hipStream_t stream)
{
    const float* x     = (const float*)d_in[0];
    const float* w_bin = (const float*)d_in[1];
    const float* w1x1  = (const float*)d_in[2];
    const float* b1x1  = (const float*)d_in[3];
    const float* gamma = (const float*)d_in[4];
    const float* beta  = (const float*)d_in[5];
    float* out = (float*)d_out;
    unsigned char* wt = (unsigned char*)d_ws;
    float* stats = (float*)((char*)d_ws + WT_BYTES);

    kw_merge<<<64, dim3(64, 9), 0, stream>>>(w_bin, w1x1, wt);
    k1_conv<<<dim3(2, 56, NB), 256, 0, stream>>>(x, wt, b1x1, out);
    k2_stats<<<512, 256, 0, stream>>>(out, stats);
    k3_bn<<<2048, 256, 0, stream>>>(out, stats, gamma, beta);
}

// Round 7
// 300.087 us; speedup vs baseline: 3.0365x; 1.3272x over previous
//
#include <hip/hip_runtime.h>

#define EPS 1e-5f
#define NB 8
#define NC 64
#define NH 224
#define NW 224
#define PLANE (NH*NW)            // 50176
#define NPIX (NB*PLANE)          // 401408
#define OUT_ELEMS (NB*NC*PLANE)  // 25690112

typedef __attribute__((ext_vector_type(8)))  short short8;
typedef __attribute__((ext_vector_type(16))) float floatx16;
typedef unsigned int u32;

// bf16 helpers (RNE)
__device__ __forceinline__ unsigned short f2bf(float f) {
    unsigned u = __float_as_uint(f);
    unsigned r = (u + 0x7fffu + ((u >> 16) & 1u)) >> 16;
    return (unsigned short)r;
}
__device__ __forceinline__ float bf2f(unsigned short s) {
    return __uint_as_float(((unsigned)s) << 16);
}

// ws layout (bytes):
//   [0, 147456)    wt: [tap 9][chunk 4] slabs of 4096B:
//                  { wh[oc 64][icl 16] 2048B | wl[oc 64][icl 16] 2048B }
//   [147456,+512)  stats: 64 sum + 64 sumsq floats
#define WT_BYTES (9*4*4096)

// ---------------------------------------------------------------------------
// KW: merge 1x1 into 3x3 (Wm[o][i][tap] = sum_k w1[o][k]*wb[k][i][tap]);
// hi/lo bf16 split of weights. LDS-staged for speed. Zeroes stats.
__global__ __launch_bounds__(256)
void kw_merge(const float* __restrict__ w_bin,
              const float* __restrict__ w1x1,
              unsigned char* __restrict__ ws)
{
    __shared__ float w1[4096];   // [oc][k]
    __shared__ float wb[576];    // [k][tap] for this ic
    const int ic  = blockIdx.x;
    const int tid = threadIdx.x;
    for (int i = tid; i < 4096; i += 256) w1[i] = w1x1[i];
    for (int i = tid; i < 576; i += 256) {
        const int k = i / 9, tap = i % 9;
        wb[i] = w_bin[(k*64 + ic)*9 + tap];
    }
    __syncthreads();
    for (int i = tid; i < 576; i += 256) {
        const int oc = i / 9, tap = i % 9;
        float acc = 0.f;
#pragma unroll
        for (int k = 0; k < 64; ++k) acc += w1[oc*64 + k] * wb[k*9 + tap];
        const unsigned short wh = f2bf(acc);
        const unsigned short wl = f2bf(acc - bf2f(wh));
        const int base = (tap*4 + (ic >> 4)) * 4096;
        const int sb   = oc*32 + (ic & 15)*2;
        *(unsigned short*)(ws + base + sb)        = wh;
        *(unsigned short*)(ws + base + 2048 + sb) = wl;
    }
    if (ic == 0 && tid < 128)
        ((float*)(ws + WT_BYTES))[tid] = 0.f;
}

// ---------------------------------------------------------------------------
// K1: merged conv via bf16 MFMA, 2 products (wh*xh + wl*xh: exact-ish weights,
// bf16 x). Block = 2 rows x 128 cols x 64 oc; 4 waves = (row, colhalf);
// wave tile = 1 row x 64 cols x 64 oc, acc[2 mf][2 nf] (64 AGPR).
// Fused per-channel sum/sumsq (k2 eliminated).
// LDS x slab: [hh 2][rr 4][cc 130] granules of 16B (8 ic), conflict-free b128.
#define XS_W  130
#define XS_SLAB (2*4*XS_W*16)   // 16640 B

__global__ __launch_bounds__(256, 3)
void k1_conv(const float* __restrict__ x,
             const unsigned char* __restrict__ wt,
             const float* __restrict__ b1x1,
             float* __restrict__ y,
             float* __restrict__ stats)
{
    __shared__ char smem[XS_SLAB];
    const int tid  = threadIdx.x;
    const int w    = tid >> 6;
    const int wrow = w & 1;            // wave's row within block
    const int ch   = w >> 1;           // wave's col-half (64 cols)
    const int lane = tid & 63;
    const int l31  = lane & 31;
    const int h    = lane >> 5;        // k-half (also oc +4h in C/D rows)
    const int c0   = blockIdx.x * 96;  // col strips [0,128) and [96,224)
    const int r0   = blockIdx.y * 2;
    const int b    = blockIdx.z;

    floatx16 c[2][2];
#pragma unroll
    for (int mf = 0; mf < 2; ++mf)
#pragma unroll
        for (int r = 0; r < 16; ++r) {
            const int oc = mf*32 + (r & 3) + 8*(r >> 2) + 4*h;
            const float bias = b1x1[oc];
            c[mf][0][r] = bias;
            c[mf][1][r] = bias;
        }

    const unsigned alane = (unsigned)(l31*32 + (h << 4));
    auto ldA = [&](int slab, int part) -> short8 {
        return *(const short8*)(wt + (size_t)slab*4096u + (unsigned)part + alane);
    };
    short8 ah0 = ldA(0, 0), ah1 = ldA(0, 1024), al0 = ldA(0, 2048), al1 = ldA(0, 3072);

#pragma unroll 1
    for (int chunk = 0; chunk < 4; ++chunk) {
        __syncthreads();   // previous chunk's LDS reads complete
        // ---- stage x chunk: one 16B granule (8 ic) per thread-iter ----
        const float* xc = x + (size_t)(b*NC + chunk*16)*PLANE;
#pragma unroll 1
        for (int i = tid; i < 2*4*XS_W; i += 256) {      // 1040 granules
            const int cc = i % XS_W;
            const int t  = i / XS_W;       // hh*4 + rr
            const int rr = t & 3;
            const int hh = t >> 2;
            const int gr = r0 - 1 + rr;
            const int gc = c0 - 1 + cc;
            unsigned short hv[8];
            if ((unsigned)gr < (unsigned)NH && (unsigned)gc < (unsigned)NW) {
                const float* p = xc + (size_t)(hh*8)*PLANE + (size_t)gr*NW + gc;
#pragma unroll
                for (int e = 0; e < 8; ++e) hv[e] = f2bf(p[(size_t)e*PLANE]);
            } else {
#pragma unroll
                for (int e = 0; e < 8; ++e) hv[e] = 0;
            }
            short8 sv;
#pragma unroll
            for (int e = 0; e < 8; ++e) sv[e] = (short)hv[e];
            *(short8*)(smem + (size_t)(t*XS_W + cc)*16u) = sv;
        }
        __syncthreads();   // xs ready

#pragma unroll 1
        for (int tap = 0; tap < 9; ++tap) {
            // prefetch next tap's A fragments (global->reg, L1/L2-hot)
            int ntap = tap + 1, nchunk = chunk;
            if (ntap == 9) { ntap = 0; nchunk = chunk + 1; }
            short8 nh0 = ah0, nh1 = ah1, nl0 = al0, nl1 = al1;
            if (nchunk < 4) {
                const int ns = ntap*4 + nchunk;
                nh0 = ldA(ns, 0);    nh1 = ldA(ns, 1024);
                nl0 = ldA(ns, 2048); nl1 = ldA(ns, 3072);
            }

            const int dy = tap / 3, dx = tap - dy*3;
            const unsigned bbase =
                ((unsigned)(h*4 + wrow + dy)*XS_W + (unsigned)(dx + ch*64 + l31))*16u;
#pragma unroll
            for (int nf = 0; nf < 2; ++nf) {
                short8 bb = *(const short8*)(smem + bbase + (unsigned)nf*512u);
                c[0][nf] = __builtin_amdgcn_mfma_f32_32x32x16_bf16(ah0, bb, c[0][nf], 0, 0, 0);
                c[1][nf] = __builtin_amdgcn_mfma_f32_32x32x16_bf16(ah1, bb, c[1][nf], 0, 0, 0);
                c[0][nf] = __builtin_amdgcn_mfma_f32_32x32x16_bf16(al0, bb, c[0][nf], 0, 0, 0);
                c[1][nf] = __builtin_amdgcn_mfma_f32_32x32x16_bf16(al1, bb, c[1][nf], 0, 0, 0);
            }
            ah0 = nh0; ah1 = nh1; al0 = nl0; al1 = nl1;
        }
    }

    // ---- epilogue: store y ----
    const int row = r0 + wrow;
#pragma unroll
    for (int mf = 0; mf < 2; ++mf)
#pragma unroll
        for (int r = 0; r < 16; ++r) {
            const int oc = mf*32 + (r & 3) + 8*(r >> 2) + 4*h;
            float* yp = y + ((size_t)(b*NC + oc)*NH + row)*NW + c0 + ch*64 + l31;
            yp[0]  = c[mf][0][r];
            yp[32] = c[mf][1][r];
        }

    // ---- fused stats: per-channel sum/sumsq (each pixel counted once) ----
    // strip B (c0!=0) duplicates block-cols <32 (global 96..127) -> mask ch0/nf0.
    const float m0 = (c0 != 0 && ch == 0) ? 0.f : 1.f;
    __syncthreads();                   // all MFMA LDS reads done; reuse smem
    float* sst = (float*)smem;         // [wave 4][128]: sum[oc] | sq[oc]
#pragma unroll
    for (int mf = 0; mf < 2; ++mf)
#pragma unroll
        for (int r = 0; r < 16; ++r) {
            const float v0 = c[mf][0][r], v1 = c[mf][1][r];
            float p = m0*v0 + v1;
            float q = m0*v0*v0 + v1*v1;
#pragma unroll
            for (int off = 1; off < 32; off <<= 1) {     // reduce within 32-lane half
                p += __shfl_xor(p, off);
                q += __shfl_xor(q, off);
            }
            if (l31 == 0) {
                const int oc = mf*32 + (r & 3) + 8*(r >> 2) + 4*h;
                sst[w*128 + oc]      = p;
                sst[w*128 + 64 + oc] = q;
            }
        }
    __syncthreads();
    if (tid < 128) {
        const float s = sst[tid] + sst[128 + tid] + sst[256 + tid] + sst[384 + tid];
        atomicAdd(&stats[tid], s);
    }
}

// ---------------------------------------------------------------------------
// K3: BN (batch stats) + leaky + clamp (== clamp(t,0,255)).
// Block = one (b, c) plane -> uniform scale/shift, scalar-hoisted.
__global__ __launch_bounds__(256)
void k3_bn(float* __restrict__ y, const float* __restrict__ stats,
           const float* __restrict__ gamma, const float* __restrict__ beta)
{
    const int cch = blockIdx.x & 63;
    const int b   = blockIdx.x >> 6;
    const float inv_n = 1.f / (float)NPIX;
    const float mean = stats[cch] * inv_n;
    const float var  = stats[64 + cch] * inv_n - mean*mean;
    const float sc   = gamma[cch] * rsqrtf(var + EPS);
    const float sh   = beta[cch] - mean*sc;
    float4* p = (float4*)(y + (size_t)(b*NC + cch)*PLANE);
    for (int i = threadIdx.x; i < PLANE/4; i += 256) {
        float4 v = p[i];
        v.x = fminf(fmaxf(v.x*sc + sh, 0.f), 255.f);
        v.y = fminf(fmaxf(v.y*sc + sh, 0.f), 255.f);
        v.z = fminf(fmaxf(v.z*sc + sh, 0.f), 255.f);
        v.w = fminf(fmaxf(v.w*sc + sh, 0.f), 255.f);
        p[i] = v;
    }
}

// ---------------------------------------------------------------------------
extern "C" void kernel_launch(void* const* d_in, const int* in_sizes, int n_in,
                              void* d_out, int out_size, void* d_ws, size_t ws_size,
                              hipStream_t stream)
{
    const float* x     = (const float*)d_in[0];
    const float* w_bin = (const float*)d_in[1];
    const float* w1x1  = (const float*)d_in[2];
    const float* b1x1  = (const float*)d_in[3];
    const float* gamma = (const float*)d_in[4];
    const float* beta  = (const float*)d_in[5];
    float* out = (float*)d_out;
    unsigned char* wt = (unsigned char*)d_ws;
    float* stats = (float*)((char*)d_ws + WT_BYTES);

    kw_merge<<<64, 256, 0, stream>>>(w_bin, w1x1, wt);
    k1_conv<<<dim3(2, 112, NB), 256, 0, stream>>>(x, wt, b1x1, out, stats);
    k3_bn<<<512, 256, 0, stream>>>(out, stats, gamma, beta);
}